// Round 1
// baseline (395.451 us; speedup 1.0000x reference)
//
#include <hip/hip_runtime.h>
#include <stdint.h>

#define B_   4
#define C_   256
#define HW_  16384
#define P_   2048
#define THR_ 0.8f

// inv = 1/sqrt(1 + 1e-5) in f32
#define INV_ 0.9999950000374997f

// ---------------- workspace layout (bytes) ----------------
// 0        : int   ncand[4]
// 256      : u64   cand[4][HW_]      (512 KB)
// 524544   : int   topk[4][P_]       (32 KB)
// 557312   : int   pos[4][HW_]       (256 KB)
// 819456   : float g [4][P_][C_]     (8 MB)
// 9208064  : float z2[4][P_][C_]     (8 MB)
// 17596672 : float r [4][C_][P_]     (8 MB)
#define OFF_NCAND 0
#define OFF_CAND  256
#define OFF_TOPK  524544
#define OFF_POS   557312
#define OFF_G     819456
#define OFF_Z2    9208064
#define OFF_R     17596672

__global__ __launch_bounds__(256) void zero_ws_kernel(int* __restrict__ pos, int* __restrict__ ncand) {
    int i = blockIdx.x * 256 + threadIdx.x;
    if (i < B_ * HW_) pos[i] = 0;
    if (i < B_) ncand[i] = 0;
}

__global__ __launch_bounds__(256) void compact_kernel(const float* __restrict__ edge,
                                                      unsigned long long* __restrict__ cand,
                                                      int* __restrict__ ncand) {
    int b = blockIdx.x >> 6;                 // 64 blocks per batch
    int i = (blockIdx.x & 63) * 256 + threadIdx.x;
    float e = edge[b * HW_ + i];
    if (e >= THR_) {
        int slot = atomicAdd(&ncand[b], 1);
        unsigned int vb = __float_as_uint(e);   // e > 0 -> bits preserve order
        cand[(size_t)b * HW_ + slot] =
            ((unsigned long long)vb << 32) | (unsigned long long)(0xFFFFFFFFu - (unsigned)i);
    }
}

// rank each candidate by (value desc, index asc); rank < P -> topk[rank] = index
__global__ __launch_bounds__(256) void rank_kernel(const unsigned long long* __restrict__ cand,
                                                   const int* __restrict__ ncand,
                                                   int* __restrict__ topk) {
    int b = blockIdx.y;
    int n = ncand[b];
    if ((int)blockIdx.x * 256 >= n) return;   // uniform exit, before any barrier
    int j = blockIdx.x * 256 + threadIdx.x;
    const unsigned long long* cb = cand + (size_t)b * HW_;
    unsigned long long kj = (j < n) ? cb[j] : 0ull;
    __shared__ unsigned long long tile[256];
    int rank = 0;
    for (int t = 0; t < n; t += 256) {
        int m = min(256, n - t);
        __syncthreads();
        if (t + (int)threadIdx.x < n) tile[threadIdx.x] = cb[t + threadIdx.x];
        __syncthreads();
        for (int k = 0; k < m; ++k) rank += (tile[k] > kj) ? 1 : 0;
    }
    if (j < n && rank < P_) topk[b * P_ + rank] = (int)(0xFFFFFFFFu - (unsigned)(kj & 0xFFFFFFFFull));
}

// if fewer than P candidates: remaining slots are zeros, tie-break ascending index
__global__ void fallback_kernel(const float* __restrict__ edge,
                                const int* __restrict__ ncand,
                                int* __restrict__ topk) {
    int b = blockIdx.x;
    int n = ncand[b];
    if (n >= P_) return;
    if (threadIdx.x != 0) return;
    int cnt = n;
    for (int i = 0; i < HW_ && cnt < P_; ++i) {
        if (edge[b * HW_ + i] < THR_) topk[b * P_ + cnt++] = i;
    }
}

__global__ __launch_bounds__(256) void scatter_pos_kernel(const int* __restrict__ topk,
                                                          int* __restrict__ pos) {
    int t = blockIdx.x * 256 + threadIdx.x;   // 0 .. B*P-1
    int b = t >> 11;
    int p = t & (P_ - 1);
    pos[b * HW_ + topk[t]] = p + 1;
}

__global__ __launch_bounds__(256) void gather_kernel(const float* __restrict__ x,
                                                     const int* __restrict__ topk,
                                                     float* __restrict__ g) {
    int blk = blockIdx.x;                     // b*P + p
    int b = blk >> 11;
    int hw = topk[blk];
    int c = threadIdx.x;
    g[(size_t)blk * C_ + c] = x[((size_t)b * C_ + c) * HW_ + hw];
}

// z2[b][o][c] = relu( (sum_p Wadj[o][p] * g[b][p][c]) * inv * ga[o] + be[o] ) + g[b][o][c]
__global__ __launch_bounds__(256) void gemm1_kernel(const float* __restrict__ Wadj,
                                                    const float* __restrict__ ga,
                                                    const float* __restrict__ be,
                                                    const float* __restrict__ g,
                                                    float* __restrict__ z2) {
    const int bm = blockIdx.x;   // o tile: 0..31
    const int bn = blockIdx.y;   // c tile: 0..3
    const int b  = blockIdx.z;
    const int tid = threadIdx.x;
    const int tx = tid & 15, ty = tid >> 4;

    __shared__ float As[16][68];
    __shared__ float Bs[16][68];

    float acc[4][4] = {};
    const float* gb = g + (size_t)b * P_ * C_;

    const int arow = tid >> 2;        // 0..63
    const int acg  = (tid & 3) * 4;   // 0,4,8,12
    const int brow = tid >> 4;        // 0..15
    const int bcg  = (tid & 15) * 4;  // 0..60

    for (int kt = 0; kt < P_; kt += 16) {
        float4 a4 = *(const float4*)&Wadj[(size_t)(bm * 64 + arow) * P_ + kt + acg];
        float4 b4 = *(const float4*)&gb[(size_t)(kt + brow) * C_ + bn * 64 + bcg];
        As[acg + 0][arow] = a4.x;
        As[acg + 1][arow] = a4.y;
        As[acg + 2][arow] = a4.z;
        As[acg + 3][arow] = a4.w;
        *(float4*)&Bs[brow][bcg] = b4;
        __syncthreads();
#pragma unroll
        for (int k = 0; k < 16; ++k) {
            float4 av = *(const float4*)&As[k][ty * 4];
            float4 bv = *(const float4*)&Bs[k][tx * 4];
            float am[4] = {av.x, av.y, av.z, av.w};
            float bm_[4] = {bv.x, bv.y, bv.z, bv.w};
#pragma unroll
            for (int i = 0; i < 4; ++i)
#pragma unroll
                for (int j = 0; j < 4; ++j)
                    acc[i][j] = fmaf(am[i], bm_[j], acc[i][j]);
        }
        __syncthreads();
    }

    float* z2b = z2 + (size_t)b * P_ * C_;
#pragma unroll
    for (int i = 0; i < 4; ++i) {
        int o = bm * 64 + ty * 4 + i;
        float gam = ga[o] * INV_;
        float bet = be[o];
        int c0 = bn * 64 + tx * 4;
        float4 gres = *(const float4*)&gb[(size_t)o * C_ + c0];
        float4 ov;
        ov.x = fmaxf(fmaf(acc[i][0], gam, bet), 0.f) + gres.x;
        ov.y = fmaxf(fmaf(acc[i][1], gam, bet), 0.f) + gres.y;
        ov.z = fmaxf(fmaf(acc[i][2], gam, bet), 0.f) + gres.z;
        ov.w = fmaxf(fmaf(acc[i][3], gam, bet), 0.f) + gres.w;
        *(float4*)&z2b[(size_t)o * C_ + c0] = ov;
    }
}

// r[b][d][p] = relu( (sum_c Wg[d][c] * z2[b][p][c]) * inv * gw[d] + bw[d] )
__global__ __launch_bounds__(256) void gemm2_kernel(const float* __restrict__ Wg,
                                                    const float* __restrict__ gw,
                                                    const float* __restrict__ bw,
                                                    const float* __restrict__ z2,
                                                    float* __restrict__ r) {
    const int bm = blockIdx.x;   // d tile: 0..3
    const int bn = blockIdx.y;   // p tile: 0..31
    const int b  = blockIdx.z;
    const int tid = threadIdx.x;
    const int tx = tid & 15, ty = tid >> 4;

    __shared__ float As[16][68];
    __shared__ float Bs[16][68];

    float acc[4][4] = {};
    const float* z2b = z2 + (size_t)b * P_ * C_;

    const int arow = tid >> 2;        // 0..63
    const int acg  = (tid & 3) * 4;   // 0,4,8,12
    const int bp   = tid >> 2;        // 0..63 (p within tile)
    const int bcg  = (tid & 3) * 4;   // c chunk

    for (int kt = 0; kt < C_; kt += 16) {
        float4 a4 = *(const float4*)&Wg[(size_t)(bm * 64 + arow) * C_ + kt + acg];
        float4 b4 = *(const float4*)&z2b[(size_t)(bn * 64 + bp) * C_ + kt + bcg];
        As[acg + 0][arow] = a4.x;
        As[acg + 1][arow] = a4.y;
        As[acg + 2][arow] = a4.z;
        As[acg + 3][arow] = a4.w;
        Bs[bcg + 0][bp] = b4.x;
        Bs[bcg + 1][bp] = b4.y;
        Bs[bcg + 2][bp] = b4.z;
        Bs[bcg + 3][bp] = b4.w;
        __syncthreads();
#pragma unroll
        for (int k = 0; k < 16; ++k) {
            float4 av = *(const float4*)&As[k][ty * 4];
            float4 bv = *(const float4*)&Bs[k][tx * 4];
            float am[4] = {av.x, av.y, av.z, av.w};
            float bm_[4] = {bv.x, bv.y, bv.z, bv.w};
#pragma unroll
            for (int i = 0; i < 4; ++i)
#pragma unroll
                for (int j = 0; j < 4; ++j)
                    acc[i][j] = fmaf(am[i], bm_[j], acc[i][j]);
        }
        __syncthreads();
    }

    float* rb = r + (size_t)b * C_ * P_;
#pragma unroll
    for (int i = 0; i < 4; ++i) {
        int d = bm * 64 + ty * 4 + i;
        float gam = gw[d] * INV_;
        float bet = bw[d];
        int p0 = bn * 64 + tx * 4;
        float4 ov;
        ov.x = fmaxf(fmaf(acc[i][0], gam, bet), 0.f);
        ov.y = fmaxf(fmaf(acc[i][1], gam, bet), 0.f);
        ov.z = fmaxf(fmaf(acc[i][2], gam, bet), 0.f);
        ov.w = fmaxf(fmaf(acc[i][3], gam, bet), 0.f);
        *(float4*)&rb[(size_t)d * P_ + p0] = ov;
    }
}

// out[b][d][hw] = pos[b][hw] ? r[b][d][pos-1] : x[b][d][hw]
__global__ __launch_bounds__(256) void output_kernel(const float* __restrict__ x,
                                                     const int* __restrict__ pos,
                                                     const float* __restrict__ r,
                                                     float* __restrict__ out) {
    size_t v = (size_t)blockIdx.x * 256 + threadIdx.x;   // float4 index
    size_t e0 = v * 4;
    int hw = (int)(e0 & (HW_ - 1));
    int bc = (int)(e0 >> 14);
    int d = bc & (C_ - 1);
    int b = bc >> 8;
    float4 xv = *(const float4*)&x[e0];
    int4 pv = *(const int4*)&pos[b * HW_ + hw];
    const float* rrow = r + ((size_t)b * C_ + d) * P_;
    float4 ov = xv;
    if (pv.x) ov.x = rrow[pv.x - 1];
    if (pv.y) ov.y = rrow[pv.y - 1];
    if (pv.z) ov.z = rrow[pv.z - 1];
    if (pv.w) ov.w = rrow[pv.w - 1];
    *(float4*)&out[e0] = ov;
}

extern "C" void kernel_launch(void* const* d_in, const int* in_sizes, int n_in,
                              void* d_out, int out_size, void* d_ws, size_t ws_size,
                              hipStream_t stream) {
    const float* x    = (const float*)d_in[0];
    const float* edge = (const float*)d_in[1];
    const float* Wadj = (const float*)d_in[2];
    const float* ga   = (const float*)d_in[3];
    const float* be   = (const float*)d_in[4];
    const float* Wg   = (const float*)d_in[5];
    const float* gw   = (const float*)d_in[6];
    const float* bw   = (const float*)d_in[7];
    float* out = (float*)d_out;

    char* ws = (char*)d_ws;
    int*                ncand = (int*)(ws + OFF_NCAND);
    unsigned long long* cand  = (unsigned long long*)(ws + OFF_CAND);
    int*                topk  = (int*)(ws + OFF_TOPK);
    int*                pos   = (int*)(ws + OFF_POS);
    float*              g     = (float*)(ws + OFF_G);
    float*              z2    = (float*)(ws + OFF_Z2);
    float*              r     = (float*)(ws + OFF_R);

    zero_ws_kernel<<<(B_ * HW_ + 255) / 256, 256, 0, stream>>>(pos, ncand);
    compact_kernel<<<B_ * 64, 256, 0, stream>>>(edge, cand, ncand);
    {
        dim3 grid(64, B_);
        rank_kernel<<<grid, 256, 0, stream>>>(cand, ncand, topk);
    }
    fallback_kernel<<<B_, 64, 0, stream>>>(edge, ncand, topk);
    scatter_pos_kernel<<<(B_ * P_) / 256, 256, 0, stream>>>(topk, pos);
    gather_kernel<<<B_ * P_, 256, 0, stream>>>(x, topk, g);
    {
        dim3 grid(P_ / 64, C_ / 64, B_);
        gemm1_kernel<<<grid, 256, 0, stream>>>(Wadj, ga, be, g, z2);
    }
    {
        dim3 grid(C_ / 64, P_ / 64, B_);
        gemm2_kernel<<<grid, 256, 0, stream>>>(Wg, gw, bw, z2, r);
    }
    output_kernel<<<(B_ * C_ * HW_) / 4 / 256, 256, 0, stream>>>(x, pos, r, out);
}

// Round 2
// 366.003 us; speedup vs baseline: 1.0805x; 1.0805x over previous
//
#include <hip/hip_runtime.h>
#include <stdint.h>

#define B_   4
#define C_   256
#define HW_  16384
#define P_   2048
#define THR_ 0.8f
#define INV_ 0.9999950000374997f

// ---------------- workspace layout (bytes) ----------------
#define OFF_NCAND 0
#define OFF_CAND  256                       // u64 cand[4][HW_]   512 KB
#define OFF_TOPK  524544                    // int topk[4][P_]     32 KB
#define OFF_POS   557312                    // int pos[4][HW_]    256 KB
#define OFF_G     819456                    // f32 g[4][P_][C_]     8 MB  (later aliased by r[4][C_][P_])
#define OFF_GT    9208064                   // bf16 gT[4][C_][P_]   4 MB
#define OFF_Z2    13402368                  // bf16 z2[4][P_][C_]   4 MB
#define OFF_WADJB 17596672                  // bf16 Wadj[2048][2048] 8 MB
#define OFF_WGB   25985280                  // bf16 Wg[256][256]  128 KB
#define OFF_R     OFF_G

typedef __attribute__((ext_vector_type(8))) short bf16x8;
typedef __attribute__((ext_vector_type(4))) float f32x4;

__device__ __forceinline__ ushort f2bf(float f) {
    union { float f; unsigned u; } a; a.f = f;
    unsigned r = (a.u + 0x7fffu + ((a.u >> 16) & 1u)) >> 16;   // RNE
    return (ushort)r;
}

__global__ __launch_bounds__(256) void zero_ws_kernel(int* __restrict__ pos, int* __restrict__ ncand) {
    int i = blockIdx.x * 256 + threadIdx.x;
    if (i < B_ * HW_) pos[i] = 0;
    if (i < B_) ncand[i] = 0;
}

__global__ __launch_bounds__(256) void convert_bf16_kernel(const float* __restrict__ src,
                                                           ushort* __restrict__ dst) {
    int i = blockIdx.x * 256 + threadIdx.x;     // float4 index
    float4 v = ((const float4*)src)[i];
    ushort4 o; o.x = f2bf(v.x); o.y = f2bf(v.y); o.z = f2bf(v.z); o.w = f2bf(v.w);
    ((ushort4*)dst)[i] = o;
}

__global__ __launch_bounds__(256) void compact_kernel(const float* __restrict__ edge,
                                                      unsigned long long* __restrict__ cand,
                                                      int* __restrict__ ncand) {
    int b = blockIdx.x >> 6;
    int i = (blockIdx.x & 63) * 256 + threadIdx.x;
    float e = edge[b * HW_ + i];
    if (e >= THR_) {
        int slot = atomicAdd(&ncand[b], 1);
        unsigned int vb = __float_as_uint(e);
        cand[(size_t)b * HW_ + slot] =
            ((unsigned long long)vb << 32) | (unsigned long long)(0xFFFFFFFFu - (unsigned)i);
    }
}

// rank by (value desc, index asc); rank < P -> topk[rank]=idx, pos[idx]=rank+1
__global__ __launch_bounds__(256) void rank_kernel(const unsigned long long* __restrict__ cand,
                                                   const int* __restrict__ ncand,
                                                   int* __restrict__ topk,
                                                   int* __restrict__ pos) {
    int b = blockIdx.y;
    int n = ncand[b];
    if ((int)blockIdx.x * 256 >= n) return;
    int j = blockIdx.x * 256 + threadIdx.x;
    const unsigned long long* cb = cand + (size_t)b * HW_;
    unsigned long long kj = (j < n) ? cb[j] : 0ull;
    __shared__ unsigned long long tile[256];
    int rank = 0;
    for (int t = 0; t < n; t += 256) {
        int m = min(256, n - t);
        __syncthreads();
        if (t + (int)threadIdx.x < n) tile[threadIdx.x] = cb[t + threadIdx.x];
        __syncthreads();
        for (int k = 0; k < m; ++k) rank += (tile[k] > kj) ? 1 : 0;
    }
    if (j < n && rank < P_) {
        int idx = (int)(0xFFFFFFFFu - (unsigned)(kj & 0xFFFFFFFFull));
        topk[b * P_ + rank] = idx;
        pos[b * HW_ + idx] = rank + 1;
    }
}

__global__ void fallback_kernel(const float* __restrict__ edge,
                                const int* __restrict__ ncand,
                                int* __restrict__ topk,
                                int* __restrict__ pos) {
    int b = blockIdx.x;
    int n = ncand[b];
    if (n >= P_) return;
    if (threadIdx.x != 0) return;
    int cnt = n;
    for (int i = 0; i < HW_ && cnt < P_; ++i) {
        if (edge[b * HW_ + i] < THR_) {
            topk[b * P_ + cnt] = i;
            pos[b * HW_ + i] = cnt + 1;
            cnt++;
        }
    }
}

// full coalesced scan of x: for selected locations emit g fp32 [p][c] and gT bf16 [c][p]
__global__ __launch_bounds__(256) void scan_gather_kernel(const float* __restrict__ x,
                                                          const int* __restrict__ pos,
                                                          float* __restrict__ g,
                                                          ushort* __restrict__ gT) {
    size_t v = (size_t)blockIdx.x * 256 + threadIdx.x;
    size_t e0 = v * 4;
    int hw = (int)(e0 & (HW_ - 1));
    int bc = (int)(e0 >> 14);
    int c = bc & (C_ - 1);
    int b = bc >> 8;
    float4 xv = *(const float4*)&x[e0];
    int4 pv = *(const int4*)&pos[b * HW_ + hw];
    float* gb = g + (size_t)b * P_ * C_;
    ushort* gTb = gT + ((size_t)b * C_ + c) * P_;
    if (pv.x) { gb[(size_t)(pv.x - 1) * C_ + c] = xv.x; gTb[pv.x - 1] = f2bf(xv.x); }
    if (pv.y) { gb[(size_t)(pv.y - 1) * C_ + c] = xv.y; gTb[pv.y - 1] = f2bf(xv.y); }
    if (pv.z) { gb[(size_t)(pv.z - 1) * C_ + c] = xv.z; gTb[pv.z - 1] = f2bf(xv.z); }
    if (pv.w) { gb[(size_t)(pv.w - 1) * C_ + c] = xv.w; gTb[pv.w - 1] = f2bf(xv.w); }
}

// ------------------- unified NT MFMA GEMM -------------------
// C[m][n] = sum_k A[m][k] * B[n][k]  (both k-contiguous, bf16)
// block tile 128x128, BK=64, 4 waves of 64x64 each, 16x16x32 MFMA
// MODE 1 (gemm1): out = bf16( relu(acc*gamma*INV+beta) + resid[m][n] )
// MODE 2 (gemm2): out = f32 ( relu(acc*gamma*INV+beta) )
template<int MODE, int KDIM, int LDO>
__global__ __launch_bounds__(256) void gemm_nt_kernel(
        const ushort* __restrict__ A, const ushort* __restrict__ B0, size_t strideB,
        const float* __restrict__ gamma, const float* __restrict__ beta,
        const float* __restrict__ resid0, size_t strideR,
        void* __restrict__ out0, size_t strideO) {
    const int bm = blockIdx.x, bn = blockIdx.y, b = blockIdx.z;
    const ushort* Bp = B0 + (size_t)b * strideB;

    __shared__ alignas(16) ushort As[128][72];
    __shared__ alignas(16) ushort Bs[128][72];

    const int tid = threadIdx.x;
    const int r = tid >> 1, h = tid & 1;
    const int wave = tid >> 6, lane = tid & 63;
    const int quad = lane >> 4, ln = lane & 15;
    const int wm = (wave >> 1) * 64, wn = (wave & 1) * 64;

    f32x4 acc[4][4];
#pragma unroll
    for (int i = 0; i < 4; ++i)
#pragma unroll
        for (int j = 0; j < 4; ++j) acc[i][j] = (f32x4){0.f, 0.f, 0.f, 0.f};

    const ushort* gA = A + (size_t)(bm * 128 + r) * KDIM + h * 32;
    const ushort* gB = Bp + (size_t)(bn * 128 + r) * KDIM + h * 32;
    const int sc = ((h ^ (((r >> 3) ^ (r >> 4)) & 1)) & 1) * 32;   // swizzled store col base

    int swa[4], swb[4];
#pragma unroll
    for (int i = 0; i < 4; ++i) {
        int rowa = wm + i * 16 + ln;
        swa[i] = ((rowa >> 3) ^ (rowa >> 4)) & 1;
        int rowb = wn + i * 16 + ln;
        swb[i] = ((rowb >> 3) ^ (rowb >> 4)) & 1;
    }

    uint4 ra[4], rb[4];
#pragma unroll
    for (int q = 0; q < 4; ++q) {
        ra[q] = ((const uint4*)gA)[q];
        rb[q] = ((const uint4*)gB)[q];
    }

    for (int kt = 0; kt < KDIM; kt += 64) {
        __syncthreads();   // prior iteration's fragment reads complete
#pragma unroll
        for (int q = 0; q < 4; ++q) {
            *(uint4*)&As[r][sc + q * 8] = ra[q];
            *(uint4*)&Bs[r][sc + q * 8] = rb[q];
        }
        __syncthreads();
        if (kt + 64 < KDIM) {
            gA += 64; gB += 64;
#pragma unroll
            for (int q = 0; q < 4; ++q) {
                ra[q] = ((const uint4*)gA)[q];
                rb[q] = ((const uint4*)gB)[q];
            }
        }
#pragma unroll
        for (int ks = 0; ks < 2; ++ks) {
            bf16x8 af[4], bf[4];
#pragma unroll
            for (int i = 0; i < 4; ++i)
                af[i] = *(const bf16x8*)&As[wm + i * 16 + ln][(ks ^ swa[i]) * 32 + quad * 8];
#pragma unroll
            for (int j = 0; j < 4; ++j)
                bf[j] = *(const bf16x8*)&Bs[wn + j * 16 + ln][(ks ^ swb[j]) * 32 + quad * 8];
#pragma unroll
            for (int i = 0; i < 4; ++i)
#pragma unroll
                for (int j = 0; j < 4; ++j)
                    acc[i][j] = __builtin_amdgcn_mfma_f32_16x16x32_bf16(af[i], bf[j], acc[i][j], 0, 0, 0);
        }
    }

    const int rowb0 = bm * 128 + wm, colb0 = bn * 128 + wn;
    if (MODE == 1) {
        const float* res = resid0 + (size_t)b * strideR;
        ushort* outp = (ushort*)out0 + (size_t)b * strideO;
#pragma unroll
        for (int i = 0; i < 4; ++i)
#pragma unroll
            for (int rg = 0; rg < 4; ++rg) {
                int row = rowb0 + i * 16 + quad * 4 + rg;
                float gam = gamma[row] * INV_;
                float bet = beta[row];
#pragma unroll
                for (int j = 0; j < 4; ++j) {
                    int col = colb0 + j * 16 + ln;
                    float v = fmaxf(acc[i][j][rg] * gam + bet, 0.f) + res[(size_t)row * LDO + col];
                    outp[(size_t)row * LDO + col] = f2bf(v);
                }
            }
    } else {
        float* outp = (float*)out0 + (size_t)b * strideO;
#pragma unroll
        for (int i = 0; i < 4; ++i)
#pragma unroll
            for (int rg = 0; rg < 4; ++rg) {
                int row = rowb0 + i * 16 + quad * 4 + rg;
                float gam = gamma[row] * INV_;
                float bet = beta[row];
#pragma unroll
                for (int j = 0; j < 4; ++j) {
                    int col = colb0 + j * 16 + ln;
                    outp[(size_t)row * LDO + col] = fmaxf(acc[i][j][rg] * gam + bet, 0.f);
                }
            }
    }
}

// out[b][d][hw] = pos ? r[b][d][pos-1] : x[b][d][hw]
__global__ __launch_bounds__(256) void output_kernel(const float* __restrict__ x,
                                                     const int* __restrict__ pos,
                                                     const float* __restrict__ r,
                                                     float* __restrict__ out) {
    size_t v = (size_t)blockIdx.x * 256 + threadIdx.x;
    size_t e0 = v * 4;
    int hw = (int)(e0 & (HW_ - 1));
    int bc = (int)(e0 >> 14);
    int d = bc & (C_ - 1);
    int b = bc >> 8;
    float4 xv = *(const float4*)&x[e0];
    int4 pv = *(const int4*)&pos[b * HW_ + hw];
    const float* rrow = r + ((size_t)b * C_ + d) * P_;
    float4 ov = xv;
    if (pv.x) ov.x = rrow[pv.x - 1];
    if (pv.y) ov.y = rrow[pv.y - 1];
    if (pv.z) ov.z = rrow[pv.z - 1];
    if (pv.w) ov.w = rrow[pv.w - 1];
    *(float4*)&out[e0] = ov;
}

extern "C" void kernel_launch(void* const* d_in, const int* in_sizes, int n_in,
                              void* d_out, int out_size, void* d_ws, size_t ws_size,
                              hipStream_t stream) {
    const float* x    = (const float*)d_in[0];
    const float* edge = (const float*)d_in[1];
    const float* Wadj = (const float*)d_in[2];
    const float* ga   = (const float*)d_in[3];
    const float* be   = (const float*)d_in[4];
    const float* Wg   = (const float*)d_in[5];
    const float* gw   = (const float*)d_in[6];
    const float* bw   = (const float*)d_in[7];
    float* out = (float*)d_out;

    char* ws = (char*)d_ws;
    int*                ncand = (int*)(ws + OFF_NCAND);
    unsigned long long* cand  = (unsigned long long*)(ws + OFF_CAND);
    int*                topk  = (int*)(ws + OFF_TOPK);
    int*                pos   = (int*)(ws + OFF_POS);
    float*              g     = (float*)(ws + OFF_G);
    ushort*             gT    = (ushort*)(ws + OFF_GT);
    ushort*             z2    = (ushort*)(ws + OFF_Z2);
    ushort*             WadjB = (ushort*)(ws + OFF_WADJB);
    ushort*             WgB   = (ushort*)(ws + OFF_WGB);
    float*              rbuf  = (float*)(ws + OFF_R);

    convert_bf16_kernel<<<P_ * P_ / 4 / 256, 256, 0, stream>>>(Wadj, WadjB);
    convert_bf16_kernel<<<C_ * C_ / 4 / 256, 256, 0, stream>>>(Wg, WgB);
    zero_ws_kernel<<<(B_ * HW_ + 255) / 256, 256, 0, stream>>>(pos, ncand);
    compact_kernel<<<B_ * 64, 256, 0, stream>>>(edge, cand, ncand);
    {
        dim3 grid(64, B_);
        rank_kernel<<<grid, 256, 0, stream>>>(cand, ncand, topk, pos);
    }
    fallback_kernel<<<B_, 64, 0, stream>>>(edge, ncand, topk, pos);
    scan_gather_kernel<<<(B_ * C_ * HW_) / 4 / 256, 256, 0, stream>>>(x, pos, g, gT);
    {
        dim3 grid(P_ / 128, C_ / 128, B_);   // (16, 2, 4)
        gemm_nt_kernel<1, P_, C_><<<grid, 256, 0, stream>>>(
            WadjB, gT, (size_t)C_ * P_, ga, be, g, (size_t)P_ * C_, z2, (size_t)P_ * C_);
    }
    {
        dim3 grid(C_ / 128, P_ / 128, B_);   // (2, 16, 4)
        gemm_nt_kernel<2, C_, P_><<<grid, 256, 0, stream>>>(
            WgB, z2, (size_t)P_ * C_, gw, bw, nullptr, 0, rbuf, (size_t)C_ * P_);
    }
    output_kernel<<<(B_ * C_ * HW_) / 4 / 256, 256, 0, stream>>>(x, pos, rbuf, out);
}

// Round 3
// 300.896 us; speedup vs baseline: 1.3142x; 1.2164x over previous
//
#include <hip/hip_runtime.h>
#include <stdint.h>

#define B_   4
#define C_   256
#define HW_  16384
#define P_   2048
#define THR_ 0.8f
#define INV_ 0.9999950000374997f

// ---------------- workspace layout (bytes) ----------------
#define OFF_NCAND 0
#define OFF_CAND  256                       // u64 cand[4][HW_]   512 KB
#define OFF_TOPK  524544                    // int topk[4][P_]     32 KB
#define OFF_POS   557312                    // int pos[4][HW_]    256 KB
#define OFF_G     819456                    // f32 g[4][P_][C_]     8 MB  (aliased later by r[4][C_][P_])
#define OFF_GT    9208064                   // bf16 gT[4][C_][P_]   4 MB  == [1024][2048]
#define OFF_Z2    13402368                  // bf16 z2[4][P_][C_]   4 MB  == [8192][256]
#define OFF_WADJB 17596672                  // bf16 Wadj[2048][2048] 8 MB
#define OFF_WGB   25985280                  // bf16 Wg[256][256]  128 KB
#define OFF_R     OFF_G

typedef __attribute__((ext_vector_type(8))) short bf16x8;
typedef __attribute__((ext_vector_type(4))) float f32x4;

__device__ __forceinline__ ushort f2bf(float f) {
    union { float f; unsigned u; } a; a.f = f;
    unsigned r = (a.u + 0x7fffu + ((a.u >> 16) & 1u)) >> 16;   // RNE
    return (ushort)r;
}

__global__ __launch_bounds__(256) void zero_ws_kernel(int* __restrict__ pos, int* __restrict__ ncand) {
    int i = blockIdx.x * 256 + threadIdx.x;
    if (i < B_ * HW_) pos[i] = 0;
    if (i < B_) ncand[i] = 0;
}

__global__ __launch_bounds__(256) void convert_bf16_kernel(const float* __restrict__ src,
                                                           ushort* __restrict__ dst) {
    int i = blockIdx.x * 256 + threadIdx.x;     // float4 index
    float4 v = ((const float4*)src)[i];
    ushort4 o; o.x = f2bf(v.x); o.y = f2bf(v.y); o.z = f2bf(v.z); o.w = f2bf(v.w);
    ((ushort4*)dst)[i] = o;
}

__global__ __launch_bounds__(256) void compact_kernel(const float* __restrict__ edge,
                                                      unsigned long long* __restrict__ cand,
                                                      int* __restrict__ ncand) {
    int b = blockIdx.x >> 6;
    int i = (blockIdx.x & 63) * 256 + threadIdx.x;
    float e = edge[b * HW_ + i];
    if (e >= THR_) {
        int slot = atomicAdd(&ncand[b], 1);
        unsigned int vb = __float_as_uint(e);
        cand[(size_t)b * HW_ + slot] =
            ((unsigned long long)vb << 32) | (unsigned long long)(0xFFFFFFFFu - (unsigned)i);
    }
}

// rank by (value desc, index asc); rank < P -> topk[rank]=idx, pos[idx]=rank+1
__global__ __launch_bounds__(256) void rank_kernel(const unsigned long long* __restrict__ cand,
                                                   const int* __restrict__ ncand,
                                                   int* __restrict__ topk,
                                                   int* __restrict__ pos) {
    int b = blockIdx.y;
    int n = ncand[b];
    if ((int)blockIdx.x * 256 >= n) return;
    int j = blockIdx.x * 256 + threadIdx.x;
    const unsigned long long* cb = cand + (size_t)b * HW_;
    unsigned long long kj = (j < n) ? cb[j] : 0ull;
    __shared__ unsigned long long tile[256];
    int rank = 0;
    for (int t = 0; t < n; t += 256) {
        int m = min(256, n - t);
        __syncthreads();
        if (t + (int)threadIdx.x < n) tile[threadIdx.x] = cb[t + threadIdx.x];
        __syncthreads();
        for (int k = 0; k < m; ++k) rank += (tile[k] > kj) ? 1 : 0;
    }
    if (j < n && rank < P_) {
        int idx = (int)(0xFFFFFFFFu - (unsigned)(kj & 0xFFFFFFFFull));
        topk[b * P_ + rank] = idx;
        pos[b * HW_ + idx] = rank + 1;
    }
}

__global__ void fallback_kernel(const float* __restrict__ edge,
                                const int* __restrict__ ncand,
                                int* __restrict__ topk,
                                int* __restrict__ pos) {
    int b = blockIdx.x;
    int n = ncand[b];
    if (n >= P_) return;
    if (threadIdx.x != 0) return;
    int cnt = n;
    for (int i = 0; i < HW_ && cnt < P_; ++i) {
        if (edge[b * HW_ + i] < THR_) {
            topk[b * P_ + cnt] = i;
            pos[b * HW_ + i] = cnt + 1;
            cnt++;
        }
    }
}

// full coalesced scan of x: for selected locations emit g fp32 [p][c] and gT bf16 [c][p]
__global__ __launch_bounds__(256) void scan_gather_kernel(const float* __restrict__ x,
                                                          const int* __restrict__ pos,
                                                          float* __restrict__ g,
                                                          ushort* __restrict__ gT) {
    size_t v = (size_t)blockIdx.x * 256 + threadIdx.x;
    size_t e0 = v * 4;
    int hw = (int)(e0 & (HW_ - 1));
    int bc = (int)(e0 >> 14);
    int c = bc & (C_ - 1);
    int b = bc >> 8;
    float4 xv = *(const float4*)&x[e0];
    int4 pv = *(const int4*)&pos[b * HW_ + hw];
    float* gb = g + (size_t)b * P_ * C_;
    ushort* gTb = gT + ((size_t)b * C_ + c) * P_;
    if (pv.x) { gb[(size_t)(pv.x - 1) * C_ + c] = xv.x; gTb[pv.x - 1] = f2bf(xv.x); }
    if (pv.y) { gb[(size_t)(pv.y - 1) * C_ + c] = xv.y; gTb[pv.y - 1] = f2bf(xv.y); }
    if (pv.z) { gb[(size_t)(pv.z - 1) * C_ + c] = xv.z; gTb[pv.z - 1] = f2bf(xv.z); }
    if (pv.w) { gb[(size_t)(pv.w - 1) * C_ + c] = xv.w; gTb[pv.w - 1] = f2bf(xv.w); }
}

// ------------------- per-wave NT MFMA GEMM, no LDS, no barriers -------------------
// C[m][n] = sum_k A[m][k] * B[n][k]; one wave computes a 64x64 tile.
// Fragments loaded directly from global (rows walked sequentially in k -> L1/L2 hits).
// Double register buffering: prefetch distance = 2 k-steps (16 loads in flight).
// MODE 1 (gemm1): M=2048 (o), N=1024 (b*256+c), K=2048
//                 out z2[b][o][c] = bf16( relu(acc*ga[o]*INV+be[o]) + g[b][o][c] )
// MODE 2 (gemm2): M=256 (d), N=8192 (b*2048+p), K=256
//                 out r[b][d][p] = relu(acc*gw[d]*INV+bw[d])
#define MFMA16(AB, BB)                                                              \
    _Pragma("unroll")                                                               \
    for (int i = 0; i < 4; ++i)                                                     \
    _Pragma("unroll")                                                               \
        for (int j = 0; j < 4; ++j)                                                 \
            acc[i][j] = __builtin_amdgcn_mfma_f32_16x16x32_bf16(                    \
                __builtin_bit_cast(bf16x8, AB[i]),                                  \
                __builtin_bit_cast(bf16x8, BB[j]), acc[i][j], 0, 0, 0);

template<int MODE, int KDIM, int NTN>
__global__ __launch_bounds__(64) void gemm_wave_kernel(
        const ushort* __restrict__ A, const ushort* __restrict__ B,
        const float* __restrict__ gamma, const float* __restrict__ beta,
        const float* __restrict__ resid, void* __restrict__ out) {
    constexpr int KSTEPS = KDIM / 32;
    const int bid = blockIdx.x;
    const int mt = bid / NTN;
    const int nt = bid % NTN;
    const int lane = threadIdx.x;            // 0..63
    const int quad = lane >> 4, ln = lane & 15;

    const ushort* pa[4];
    const ushort* pb[4];
#pragma unroll
    for (int i = 0; i < 4; ++i) {
        pa[i] = A + (size_t)(mt * 64 + i * 16 + ln) * KDIM + quad * 8;
        pb[i] = B + (size_t)(nt * 64 + i * 16 + ln) * KDIM + quad * 8;
    }

    f32x4 acc[4][4];
#pragma unroll
    for (int i = 0; i < 4; ++i)
#pragma unroll
        for (int j = 0; j < 4; ++j) acc[i][j] = (f32x4){0.f, 0.f, 0.f, 0.f};

    uint4 a0[4], b0[4], a1[4], b1[4];
#pragma unroll
    for (int i = 0; i < 4; ++i) {
        a0[i] = *(const uint4*)(pa[i]);
        b0[i] = *(const uint4*)(pb[i]);
        a1[i] = *(const uint4*)(pa[i] + 32);
        b1[i] = *(const uint4*)(pb[i] + 32);
    }

    int koff = 64;
    for (int s = 0; s < KSTEPS - 2; s += 2) {
        MFMA16(a0, b0)                        // step s
#pragma unroll
        for (int i = 0; i < 4; ++i) {         // prefetch step s+2
            a0[i] = *(const uint4*)(pa[i] + koff);
            b0[i] = *(const uint4*)(pb[i] + koff);
        }
        MFMA16(a1, b1)                        // step s+1
#pragma unroll
        for (int i = 0; i < 4; ++i) {         // prefetch step s+3
            a1[i] = *(const uint4*)(pa[i] + koff + 32);
            b1[i] = *(const uint4*)(pb[i] + koff + 32);
        }
        koff += 64;
    }
    MFMA16(a0, b0)                            // step KSTEPS-2
    MFMA16(a1, b1)                            // step KSTEPS-1

    // hoisted BN params per m-row
    float gm[16], bt[16];
#pragma unroll
    for (int i = 0; i < 4; ++i)
#pragma unroll
        for (int rg = 0; rg < 4; ++rg) {
            int row = mt * 64 + i * 16 + quad * 4 + rg;
            gm[i * 4 + rg] = gamma[row] * INV_;
            bt[i * 4 + rg] = beta[row];
        }

    if (MODE == 1) {
#pragma unroll
        for (int j = 0; j < 4; ++j) {
            int n = nt * 64 + j * 16 + ln;
            int bb = n >> 8;                  // batch
            int cc = n & (C_ - 1);            // channel
            const float* res = resid + (size_t)bb * P_ * C_ + cc;
            ushort* op = (ushort*)out + (size_t)bb * P_ * C_ + cc;
#pragma unroll
            for (int i = 0; i < 4; ++i)
#pragma unroll
                for (int rg = 0; rg < 4; ++rg) {
                    int row = mt * 64 + i * 16 + quad * 4 + rg;
                    float v = fmaxf(acc[i][j][rg] * gm[i * 4 + rg] + bt[i * 4 + rg], 0.f)
                              + res[(size_t)row * C_];
                    op[(size_t)row * C_] = f2bf(v);
                }
        }
    } else {
#pragma unroll
        for (int j = 0; j < 4; ++j) {
            int n = nt * 64 + j * 16 + ln;
            int bb = n >> 11;                 // batch
            int pp = n & (P_ - 1);            // p
            float* op = (float*)out + (size_t)bb * C_ * P_ + pp;
#pragma unroll
            for (int i = 0; i < 4; ++i)
#pragma unroll
                for (int rg = 0; rg < 4; ++rg) {
                    int row = mt * 64 + i * 16 + quad * 4 + rg;   // d
                    op[(size_t)row * P_] =
                        fmaxf(acc[i][j][rg] * gm[i * 4 + rg] + bt[i * 4 + rg], 0.f);
                }
        }
    }
}

// out[b][d][hw] = pos ? r[b][d][pos-1] : x[b][d][hw]
__global__ __launch_bounds__(256) void output_kernel(const float* __restrict__ x,
                                                     const int* __restrict__ pos,
                                                     const float* __restrict__ r,
                                                     float* __restrict__ out) {
    size_t v = (size_t)blockIdx.x * 256 + threadIdx.x;
    size_t e0 = v * 4;
    int hw = (int)(e0 & (HW_ - 1));
    int bc = (int)(e0 >> 14);
    int d = bc & (C_ - 1);
    int b = bc >> 8;
    float4 xv = *(const float4*)&x[e0];
    int4 pv = *(const int4*)&pos[b * HW_ + hw];
    const float* rrow = r + ((size_t)b * C_ + d) * P_;
    float4 ov = xv;
    if (pv.x) ov.x = rrow[pv.x - 1];
    if (pv.y) ov.y = rrow[pv.y - 1];
    if (pv.z) ov.z = rrow[pv.z - 1];
    if (pv.w) ov.w = rrow[pv.w - 1];
    *(float4*)&out[e0] = ov;
}

extern "C" void kernel_launch(void* const* d_in, const int* in_sizes, int n_in,
                              void* d_out, int out_size, void* d_ws, size_t ws_size,
                              hipStream_t stream) {
    const float* x    = (const float*)d_in[0];
    const float* edge = (const float*)d_in[1];
    const float* Wadj = (const float*)d_in[2];
    const float* ga   = (const float*)d_in[3];
    const float* be   = (const float*)d_in[4];
    const float* Wg   = (const float*)d_in[5];
    const float* gw   = (const float*)d_in[6];
    const float* bw   = (const float*)d_in[7];
    float* out = (float*)d_out;

    char* ws = (char*)d_ws;
    int*                ncand = (int*)(ws + OFF_NCAND);
    unsigned long long* cand  = (unsigned long long*)(ws + OFF_CAND);
    int*                topk  = (int*)(ws + OFF_TOPK);
    int*                pos   = (int*)(ws + OFF_POS);
    float*              g     = (float*)(ws + OFF_G);
    ushort*             gT    = (ushort*)(ws + OFF_GT);
    ushort*             z2    = (ushort*)(ws + OFF_Z2);
    ushort*             WadjB = (ushort*)(ws + OFF_WADJB);
    ushort*             WgB   = (ushort*)(ws + OFF_WGB);
    float*              rbuf  = (float*)(ws + OFF_R);

    convert_bf16_kernel<<<P_ * P_ / 4 / 256, 256, 0, stream>>>(Wadj, WadjB);
    convert_bf16_kernel<<<C_ * C_ / 4 / 256, 256, 0, stream>>>(Wg, WgB);
    zero_ws_kernel<<<(B_ * HW_ + 255) / 256, 256, 0, stream>>>(pos, ncand);
    compact_kernel<<<B_ * 64, 256, 0, stream>>>(edge, cand, ncand);
    {
        dim3 grid(64, B_);
        rank_kernel<<<grid, 256, 0, stream>>>(cand, ncand, topk, pos);
    }
    fallback_kernel<<<B_, 64, 0, stream>>>(edge, ncand, topk, pos);
    scan_gather_kernel<<<(B_ * C_ * HW_) / 4 / 256, 256, 0, stream>>>(x, pos, g, gT);

    // GEMM1: M=2048, N=1024 (b,c), K=2048 -> 32x16 wave tiles = 512 waves
    gemm_wave_kernel<1, 2048, 16><<<512, 64, 0, stream>>>(WadjB, gT, ga, be, g, z2);
    // GEMM2: M=256, N=8192 (b,p), K=256 -> 4x128 wave tiles = 512 waves
    gemm_wave_kernel<2, 256, 128><<<512, 64, 0, stream>>>(WgB, z2, gw, bw, nullptr, rbuf);

    output_kernel<<<(B_ * C_ * HW_) / 4 / 256, 256, 0, stream>>>(x, pos, rbuf, out);
}

// Round 4
// 265.499 us; speedup vs baseline: 1.4895x; 1.1333x over previous
//
#include <hip/hip_runtime.h>
#include <stdint.h>

#define B_   4
#define C_   256
#define HW_  16384
#define P_   2048
#define THR_ 0.8f
#define INV_ 0.9999950000374997f

// ---------------- workspace layout (bytes) ----------------
#define OFF_NCAND 0
#define OFF_CAND  256                       // u64 cand[4][HW_]   512 KB
#define OFF_TOPK  524544                    // int topk[4][P_]     32 KB
#define OFF_POS   557312                    // int pos[4][HW_]    256 KB
#define OFF_G     819456                    // f32 g[4][P_][C_]     8 MB  (aliased later by r[4][C_][P_])
#define OFF_GT    9208064                   // bf16 gT[4][C_][P_]   4 MB  == [1024][2048]
#define OFF_Z2    13402368                  // bf16 z2[4][P_][C_]   4 MB  == [8192][256]
#define OFF_WADJB 17596672                  // bf16 Wadj[2048][2048] 8 MB
#define OFF_WGB   25985280                  // bf16 Wg[256][256]  128 KB
#define OFF_R     OFF_G
#define OFF_RANK  OFF_Z2                    // int rank[4][HW_] 256 KB, aliases z2 (dead before gemm1)

typedef __attribute__((ext_vector_type(8))) short bf16x8;
typedef __attribute__((ext_vector_type(4))) float f32x4;

__device__ __forceinline__ ushort f2bf(float f) {
    union { float f; unsigned u; } a; a.f = f;
    unsigned r = (a.u + 0x7fffu + ((a.u >> 16) & 1u)) >> 16;   // RNE
    return (ushort)r;
}

__global__ __launch_bounds__(256) void zero_ws_kernel(int* __restrict__ pos,
                                                      int* __restrict__ rankbuf,
                                                      int* __restrict__ ncand) {
    int i = blockIdx.x * 256 + threadIdx.x;
    if (i < B_ * HW_) { pos[i] = 0; rankbuf[i] = 0; }
    if (i < B_) ncand[i] = 0;
}

__global__ __launch_bounds__(256) void convert_bf16_kernel(const float* __restrict__ src,
                                                           ushort* __restrict__ dst) {
    int i = blockIdx.x * 256 + threadIdx.x;     // float4 index
    float4 v = ((const float4*)src)[i];
    ushort4 o; o.x = f2bf(v.x); o.y = f2bf(v.y); o.z = f2bf(v.z); o.w = f2bf(v.w);
    ((ushort4*)dst)[i] = o;
}

__global__ __launch_bounds__(256) void compact_kernel(const float* __restrict__ edge,
                                                      unsigned long long* __restrict__ cand,
                                                      int* __restrict__ ncand) {
    int b = blockIdx.x >> 6;
    int i = (blockIdx.x & 63) * 256 + threadIdx.x;
    float e = edge[b * HW_ + i];
    if (e >= THR_) {
        int slot = atomicAdd(&ncand[b], 1);
        unsigned int vb = __float_as_uint(e);
        cand[(size_t)b * HW_ + slot] =
            ((unsigned long long)vb << 32) | (unsigned long long)(0xFFFFFFFFu - (unsigned)i);
    }
}

// 2-D partial rank: block (jb, tb, b) counts, for each candidate j in jb-tile,
// how many candidates in tb-tile compare greater. atomicAdd into rankbuf[j].
__global__ __launch_bounds__(256) void rank_partial_kernel(
        const unsigned long long* __restrict__ cand,
        const int* __restrict__ ncand,
        int* __restrict__ rankbuf) {
    int b = blockIdx.z;
    int n = ncand[b];
    int jb = blockIdx.x * 256, tb = blockIdx.y * 256;
    if (jb >= n || tb >= n) return;
    const unsigned long long* cb = cand + (size_t)b * HW_;
    __shared__ unsigned long long tile[256];
    int j = jb + threadIdx.x;
    unsigned long long kj = (j < n) ? cb[j] : 0ull;
    tile[threadIdx.x] = (tb + (int)threadIdx.x < n) ? cb[tb + threadIdx.x] : 0ull;
    __syncthreads();
    int cnt = 0;
#pragma unroll 16
    for (int k = 0; k < 256; ++k) cnt += (tile[k] > kj) ? 1 : 0;   // padded zeros never count
    if (j < n && cnt) atomicAdd(&rankbuf[b * HW_ + j], cnt);
}

// rank < P -> topk[rank]=idx, pos[idx]=rank+1
__global__ __launch_bounds__(256) void rank_finalize_kernel(
        const unsigned long long* __restrict__ cand,
        const int* __restrict__ ncand,
        const int* __restrict__ rankbuf,
        int* __restrict__ topk,
        int* __restrict__ pos) {
    int b = blockIdx.y;
    int n = ncand[b];
    int j = blockIdx.x * 256 + threadIdx.x;
    if (j >= n) return;
    int rank = rankbuf[b * HW_ + j];
    if (rank < P_) {
        int idx = (int)(0xFFFFFFFFu - (unsigned)(cand[(size_t)b * HW_ + j] & 0xFFFFFFFFull));
        topk[b * P_ + rank] = idx;
        pos[b * HW_ + idx] = rank + 1;
    }
}

__global__ void fallback_kernel(const float* __restrict__ edge,
                                const int* __restrict__ ncand,
                                int* __restrict__ topk,
                                int* __restrict__ pos) {
    int b = blockIdx.x;
    int n = ncand[b];
    if (n >= P_) return;
    if (threadIdx.x != 0) return;
    int cnt = n;
    for (int i = 0; i < HW_ && cnt < P_; ++i) {
        if (edge[b * HW_ + i] < THR_) {
            topk[b * P_ + cnt] = i;
            pos[b * HW_ + i] = cnt + 1;
            cnt++;
        }
    }
}

// full coalesced scan of x: for selected locations emit g fp32 [p][c] and gT bf16 [c][p]
__global__ __launch_bounds__(256) void scan_gather_kernel(const float* __restrict__ x,
                                                          const int* __restrict__ pos,
                                                          float* __restrict__ g,
                                                          ushort* __restrict__ gT) {
    size_t v = (size_t)blockIdx.x * 256 + threadIdx.x;
    size_t e0 = v * 4;
    int hw = (int)(e0 & (HW_ - 1));
    int bc = (int)(e0 >> 14);
    int c = bc & (C_ - 1);
    int b = bc >> 8;
    float4 xv = *(const float4*)&x[e0];
    int4 pv = *(const int4*)&pos[b * HW_ + hw];
    float* gb = g + (size_t)b * P_ * C_;
    ushort* gTb = gT + ((size_t)b * C_ + c) * P_;
    if (pv.x) { gb[(size_t)(pv.x - 1) * C_ + c] = xv.x; gTb[pv.x - 1] = f2bf(xv.x); }
    if (pv.y) { gb[(size_t)(pv.y - 1) * C_ + c] = xv.y; gTb[pv.y - 1] = f2bf(xv.y); }
    if (pv.z) { gb[(size_t)(pv.z - 1) * C_ + c] = xv.z; gTb[pv.z - 1] = f2bf(xv.z); }
    if (pv.w) { gb[(size_t)(pv.w - 1) * C_ + c] = xv.w; gTb[pv.w - 1] = f2bf(xv.w); }
}

// ------------------- per-wave NT MFMA GEMM, no LDS, no barriers -------------------
#define MFMA16(AB, BB)                                                              \
    _Pragma("unroll")                                                               \
    for (int i = 0; i < 4; ++i)                                                     \
    _Pragma("unroll")                                                               \
        for (int j = 0; j < 4; ++j)                                                 \
            acc[i][j] = __builtin_amdgcn_mfma_f32_16x16x32_bf16(                    \
                __builtin_bit_cast(bf16x8, AB[i]),                                  \
                __builtin_bit_cast(bf16x8, BB[j]), acc[i][j], 0, 0, 0);

template<int MODE, int KDIM, int NTN>
__global__ __launch_bounds__(64) void gemm_wave_kernel(
        const ushort* __restrict__ A, const ushort* __restrict__ B,
        const float* __restrict__ gamma, const float* __restrict__ beta,
        const float* __restrict__ resid, void* __restrict__ out) {
    constexpr int KSTEPS = KDIM / 32;
    const int bid = blockIdx.x;
    const int mt = bid / NTN;
    const int nt = bid % NTN;
    const int lane = threadIdx.x;            // 0..63
    const int quad = lane >> 4, ln = lane & 15;

    const ushort* pa[4];
    const ushort* pb[4];
#pragma unroll
    for (int i = 0; i < 4; ++i) {
        pa[i] = A + (size_t)(mt * 64 + i * 16 + ln) * KDIM + quad * 8;
        pb[i] = B + (size_t)(nt * 64 + i * 16 + ln) * KDIM + quad * 8;
    }

    f32x4 acc[4][4];
#pragma unroll
    for (int i = 0; i < 4; ++i)
#pragma unroll
        for (int j = 0; j < 4; ++j) acc[i][j] = (f32x4){0.f, 0.f, 0.f, 0.f};

    uint4 a0[4], b0[4], a1[4], b1[4];
#pragma unroll
    for (int i = 0; i < 4; ++i) {
        a0[i] = *(const uint4*)(pa[i]);
        b0[i] = *(const uint4*)(pb[i]);
        a1[i] = *(const uint4*)(pa[i] + 32);
        b1[i] = *(const uint4*)(pb[i] + 32);
    }

    int koff = 64;
    for (int s = 0; s < KSTEPS - 2; s += 2) {
        MFMA16(a0, b0)
#pragma unroll
        for (int i = 0; i < 4; ++i) {
            a0[i] = *(const uint4*)(pa[i] + koff);
            b0[i] = *(const uint4*)(pb[i] + koff);
        }
        MFMA16(a1, b1)
#pragma unroll
        for (int i = 0; i < 4; ++i) {
            a1[i] = *(const uint4*)(pa[i] + koff + 32);
            b1[i] = *(const uint4*)(pb[i] + koff + 32);
        }
        koff += 64;
    }
    MFMA16(a0, b0)
    MFMA16(a1, b1)

    float gm[16], bt[16];
#pragma unroll
    for (int i = 0; i < 4; ++i)
#pragma unroll
        for (int rg = 0; rg < 4; ++rg) {
            int row = mt * 64 + i * 16 + quad * 4 + rg;
            gm[i * 4 + rg] = gamma[row] * INV_;
            bt[i * 4 + rg] = beta[row];
        }

    if (MODE == 1) {
#pragma unroll
        for (int j = 0; j < 4; ++j) {
            int n = nt * 64 + j * 16 + ln;
            int bb = n >> 8;
            int cc = n & (C_ - 1);
            const float* res = resid + (size_t)bb * P_ * C_ + cc;
            ushort* op = (ushort*)out + (size_t)bb * P_ * C_ + cc;
#pragma unroll
            for (int i = 0; i < 4; ++i)
#pragma unroll
                for (int rg = 0; rg < 4; ++rg) {
                    int row = mt * 64 + i * 16 + quad * 4 + rg;
                    float v = fmaxf(acc[i][j][rg] * gm[i * 4 + rg] + bt[i * 4 + rg], 0.f)
                              + res[(size_t)row * C_];
                    op[(size_t)row * C_] = f2bf(v);
                }
        }
    } else {
#pragma unroll
        for (int j = 0; j < 4; ++j) {
            int n = nt * 64 + j * 16 + ln;
            int bb = n >> 11;
            int pp = n & (P_ - 1);
            float* op = (float*)out + (size_t)bb * C_ * P_ + pp;
#pragma unroll
            for (int i = 0; i < 4; ++i)
#pragma unroll
                for (int rg = 0; rg < 4; ++rg) {
                    int row = mt * 64 + i * 16 + quad * 4 + rg;
                    op[(size_t)row * P_] =
                        fmaxf(acc[i][j][rg] * gm[i * 4 + rg] + bt[i * 4 + rg], 0.f);
                }
        }
    }
}

// out[b][d][hw] = pos ? r[b][d][pos-1] : x[b][d][hw]
__global__ __launch_bounds__(256) void output_kernel(const float* __restrict__ x,
                                                     const int* __restrict__ pos,
                                                     const float* __restrict__ r,
                                                     float* __restrict__ out) {
    size_t v = (size_t)blockIdx.x * 256 + threadIdx.x;
    size_t e0 = v * 4;
    int hw = (int)(e0 & (HW_ - 1));
    int bc = (int)(e0 >> 14);
    int d = bc & (C_ - 1);
    int b = bc >> 8;
    float4 xv = *(const float4*)&x[e0];
    int4 pv = *(const int4*)&pos[b * HW_ + hw];
    const float* rrow = r + ((size_t)b * C_ + d) * P_;
    float4 ov = xv;
    if (pv.x) ov.x = rrow[pv.x - 1];
    if (pv.y) ov.y = rrow[pv.y - 1];
    if (pv.z) ov.z = rrow[pv.z - 1];
    if (pv.w) ov.w = rrow[pv.w - 1];
    *(float4*)&out[e0] = ov;
}

extern "C" void kernel_launch(void* const* d_in, const int* in_sizes, int n_in,
                              void* d_out, int out_size, void* d_ws, size_t ws_size,
                              hipStream_t stream) {
    const float* x    = (const float*)d_in[0];
    const float* edge = (const float*)d_in[1];
    const float* Wadj = (const float*)d_in[2];
    const float* ga   = (const float*)d_in[3];
    const float* be   = (const float*)d_in[4];
    const float* Wg   = (const float*)d_in[5];
    const float* gw   = (const float*)d_in[6];
    const float* bw   = (const float*)d_in[7];
    float* out = (float*)d_out;

    char* ws = (char*)d_ws;
    int*                ncand = (int*)(ws + OFF_NCAND);
    unsigned long long* cand  = (unsigned long long*)(ws + OFF_CAND);
    int*                topk  = (int*)(ws + OFF_TOPK);
    int*                pos   = (int*)(ws + OFF_POS);
    int*                rankb = (int*)(ws + OFF_RANK);
    float*              g     = (float*)(ws + OFF_G);
    ushort*             gT    = (ushort*)(ws + OFF_GT);
    ushort*             z2    = (ushort*)(ws + OFF_Z2);
    ushort*             WadjB = (ushort*)(ws + OFF_WADJB);
    ushort*             WgB   = (ushort*)(ws + OFF_WGB);
    float*              rbuf  = (float*)(ws + OFF_R);

    convert_bf16_kernel<<<P_ * P_ / 4 / 256, 256, 0, stream>>>(Wadj, WadjB);
    convert_bf16_kernel<<<C_ * C_ / 4 / 256, 256, 0, stream>>>(Wg, WgB);
    zero_ws_kernel<<<(B_ * HW_ + 255) / 256, 256, 0, stream>>>(pos, rankb, ncand);
    compact_kernel<<<B_ * 64, 256, 0, stream>>>(edge, cand, ncand);
    {
        dim3 grid(64, 64, B_);
        rank_partial_kernel<<<grid, 256, 0, stream>>>(cand, ncand, rankb);
    }
    {
        dim3 grid(64, B_);
        rank_finalize_kernel<<<grid, 256, 0, stream>>>(cand, ncand, rankb, topk, pos);
    }
    fallback_kernel<<<B_, 64, 0, stream>>>(edge, ncand, topk, pos);
    scan_gather_kernel<<<(B_ * C_ * HW_) / 4 / 256, 256, 0, stream>>>(x, pos, g, gT);

    // GEMM1: M=2048, N=1024 (b,c), K=2048 -> 32x16 wave tiles = 512 waves
    gemm_wave_kernel<1, 2048, 16><<<512, 64, 0, stream>>>(WadjB, gT, ga, be, g, z2);
    // GEMM2: M=256, N=8192 (b,p), K=256 -> 4x128 wave tiles = 512 waves
    gemm_wave_kernel<2, 256, 128><<<512, 64, 0, stream>>>(WgB, z2, gw, bw, nullptr, rbuf);

    output_kernel<<<(B_ * C_ * HW_) / 4 / 256, 256, 0, stream>>>(x, pos, rbuf, out);
}

// Round 5
// 235.667 us; speedup vs baseline: 1.6780x; 1.1266x over previous
//
#include <hip/hip_runtime.h>
#include <stdint.h>

#define B_   4
#define C_   256
#define HW_  16384
#define P_   2048
#define THR_ 0.8f
#define INV_ 0.9999950000374997f

// ---------------- workspace layout (bytes) ----------------
#define OFF_NCAND 0
#define OFF_CAND  256                       // u64 cand[4][HW_]   512 KB
#define OFF_TOPK  524544                    // int topk[4][P_]     32 KB
#define OFF_POS   557312                    // int pos[4][HW_]    256 KB
#define OFF_G     819456                    // f32 r[4][C_][P_]     8 MB (GEMM2 out)
#define OFF_GT    9208064                   // bf16 gT[4][C_][P_]   4 MB  == [1024][2048]
#define OFF_Z2    13402368                  // bf16 z2[4][P_][C_]   4 MB  == [8192][256]
#define OFF_WADJB 17596672                  // bf16 Wadj[2048][2048] 8 MB
#define OFF_WGB   25985280                  // bf16 Wg[256][256]  128 KB
#define OFF_R     OFF_G
#define OFF_RANK  OFF_Z2                    // int rank[4][HW_] 256 KB, aliases z2 (dead before gemm1)

typedef __attribute__((ext_vector_type(8))) short bf16x8;
typedef __attribute__((ext_vector_type(4))) float f32x4;

__device__ __forceinline__ ushort f2bf(float f) {
    union { float f; unsigned u; } a; a.f = f;
    unsigned r = (a.u + 0x7fffu + ((a.u >> 16) & 1u)) >> 16;   // RNE
    return (ushort)r;
}
__device__ __forceinline__ float bf2f(ushort u) {
    union { unsigned u; float f; } a; a.u = (unsigned)u << 16;
    return a.f;
}

__global__ __launch_bounds__(256) void zero_ws_kernel(int* __restrict__ pos,
                                                      int* __restrict__ rankbuf,
                                                      int* __restrict__ ncand) {
    int i = blockIdx.x * 256 + threadIdx.x;
    if (i < B_ * HW_) { pos[i] = 0; rankbuf[i] = 0; }
    if (i < B_) ncand[i] = 0;
}

__global__ __launch_bounds__(256) void convert_bf16_kernel(const float* __restrict__ src,
                                                           ushort* __restrict__ dst) {
    int i = blockIdx.x * 256 + threadIdx.x;     // float4 index
    float4 v = ((const float4*)src)[i];
    ushort4 o; o.x = f2bf(v.x); o.y = f2bf(v.y); o.z = f2bf(v.z); o.w = f2bf(v.w);
    ((ushort4*)dst)[i] = o;
}

__global__ __launch_bounds__(256) void compact_kernel(const float* __restrict__ edge,
                                                      unsigned long long* __restrict__ cand,
                                                      int* __restrict__ ncand) {
    int b = blockIdx.x >> 6;
    int i = (blockIdx.x & 63) * 256 + threadIdx.x;
    float e = edge[b * HW_ + i];
    if (e >= THR_) {
        int slot = atomicAdd(&ncand[b], 1);
        unsigned int vb = __float_as_uint(e);
        cand[(size_t)b * HW_ + slot] =
            ((unsigned long long)vb << 32) | (unsigned long long)(0xFFFFFFFFu - (unsigned)i);
    }
}

// 2-D partial rank: block (jb, tb, b) counts, for each candidate j in jb-tile,
// how many candidates in tb-tile compare greater. atomicAdd into rankbuf[j].
__global__ __launch_bounds__(256) void rank_partial_kernel(
        const unsigned long long* __restrict__ cand,
        const int* __restrict__ ncand,
        int* __restrict__ rankbuf) {
    int b = blockIdx.z;
    int n = ncand[b];
    int jb = blockIdx.x * 256, tb = blockIdx.y * 256;
    if (jb >= n || tb >= n) return;
    const unsigned long long* cb = cand + (size_t)b * HW_;
    __shared__ unsigned long long tile[256];
    int j = jb + threadIdx.x;
    unsigned long long kj = (j < n) ? cb[j] : 0ull;
    tile[threadIdx.x] = (tb + (int)threadIdx.x < n) ? cb[tb + threadIdx.x] : 0ull;
    __syncthreads();
    int cnt = 0;
#pragma unroll 16
    for (int k = 0; k < 256; ++k) cnt += (tile[k] > kj) ? 1 : 0;   // padded zeros never count
    if (j < n && cnt) atomicAdd(&rankbuf[b * HW_ + j], cnt);
}

// rank < P -> topk[rank]=idx, pos[idx]=rank+1
__global__ __launch_bounds__(256) void rank_finalize_kernel(
        const unsigned long long* __restrict__ cand,
        const int* __restrict__ ncand,
        const int* __restrict__ rankbuf,
        int* __restrict__ topk,
        int* __restrict__ pos) {
    int b = blockIdx.y;
    int n = ncand[b];
    int j = blockIdx.x * 256 + threadIdx.x;
    if (j >= n) return;
    int rank = rankbuf[b * HW_ + j];
    if (rank < P_) {
        int idx = (int)(0xFFFFFFFFu - (unsigned)(cand[(size_t)b * HW_ + j] & 0xFFFFFFFFull));
        topk[b * P_ + rank] = idx;
        pos[b * HW_ + idx] = rank + 1;
    }
}

__global__ void fallback_kernel(const float* __restrict__ edge,
                                const int* __restrict__ ncand,
                                int* __restrict__ topk,
                                int* __restrict__ pos) {
    int b = blockIdx.x;
    int n = ncand[b];
    if (n >= P_) return;
    if (threadIdx.x != 0) return;
    int cnt = n;
    for (int i = 0; i < HW_ && cnt < P_; ++i) {
        if (edge[b * HW_ + i] < THR_) {
            topk[b * P_ + cnt] = i;
            pos[b * HW_ + i] = cnt + 1;
            cnt++;
        }
    }
}

// index-driven gather: one block per (b,c) row; stage x-row in LDS (coalesced),
// gather topk positions from LDS, write gT row fully coalesced (16B/thread runs).
__global__ __launch_bounds__(256) void gather_lds_kernel(const float* __restrict__ x,
                                                         const int* __restrict__ topk,
                                                         ushort* __restrict__ gT) {
    __shared__ float row[HW_];              // 64 KB -> 2 blocks/CU
    int bc = blockIdx.x;                    // b*C_ + c
    int b = bc >> 8;
    const float* xr = x + (size_t)bc * HW_;
#pragma unroll
    for (int i = 0; i < 16; ++i)
        ((float4*)row)[threadIdx.x + i * 256] = ((const float4*)xr)[threadIdx.x + i * 256];
    __syncthreads();
    const int* tk = topk + b * P_;
    int p0 = threadIdx.x * 8;
    int4 i0 = *(const int4*)&tk[p0];
    int4 i1 = *(const int4*)&tk[p0 + 4];
    ushort4 o0, o1;
    o0.x = f2bf(row[i0.x]); o0.y = f2bf(row[i0.y]); o0.z = f2bf(row[i0.z]); o0.w = f2bf(row[i0.w]);
    o1.x = f2bf(row[i1.x]); o1.y = f2bf(row[i1.y]); o1.z = f2bf(row[i1.z]); o1.w = f2bf(row[i1.w]);
    ushort* gp = gT + (size_t)bc * P_ + p0;
    *(ushort4*)gp = o0;
    *(ushort4*)(gp + 4) = o1;
}

// ------------------- per-wave NT MFMA GEMM, no LDS, no barriers -------------------
#define MFMA16(AB, BB)                                                              \
    _Pragma("unroll")                                                               \
    for (int i = 0; i < 4; ++i)                                                     \
    _Pragma("unroll")                                                               \
        for (int j = 0; j < 4; ++j)                                                 \
            acc[i][j] = __builtin_amdgcn_mfma_f32_16x16x32_bf16(                    \
                __builtin_bit_cast(bf16x8, AB[i]),                                  \
                __builtin_bit_cast(bf16x8, BB[j]), acc[i][j], 0, 0, 0);

// MODE 1 (gemm1): M=2048 (o), N=1024 (b*256+c), K=2048
//                 z2[b][o][c] = bf16( relu(acc*ga[o]*INV+be[o]) + bf2f(gT[(b,c)][o]) )
// MODE 2 (gemm2): M=256 (d), N=8192 (b*2048+p), K=256
//                 r[b][d][p] = relu(acc*gw[d]*INV+bw[d])
template<int MODE, int KDIM, int NTN>
__global__ __launch_bounds__(64) void gemm_wave_kernel(
        const ushort* __restrict__ A, const ushort* __restrict__ B,
        const float* __restrict__ gamma, const float* __restrict__ beta,
        const ushort* __restrict__ residT, void* __restrict__ out) {
    constexpr int KSTEPS = KDIM / 32;
    const int bid = blockIdx.x;
    const int mt = bid / NTN;
    const int nt = bid % NTN;
    const int lane = threadIdx.x;            // 0..63
    const int quad = lane >> 4, ln = lane & 15;

    const ushort* pa[4];
    const ushort* pb[4];
#pragma unroll
    for (int i = 0; i < 4; ++i) {
        pa[i] = A + (size_t)(mt * 64 + i * 16 + ln) * KDIM + quad * 8;
        pb[i] = B + (size_t)(nt * 64 + i * 16 + ln) * KDIM + quad * 8;
    }

    f32x4 acc[4][4];
#pragma unroll
    for (int i = 0; i < 4; ++i)
#pragma unroll
        for (int j = 0; j < 4; ++j) acc[i][j] = (f32x4){0.f, 0.f, 0.f, 0.f};

    uint4 a0[4], b0[4], a1[4], b1[4];
#pragma unroll
    for (int i = 0; i < 4; ++i) {
        a0[i] = *(const uint4*)(pa[i]);
        b0[i] = *(const uint4*)(pb[i]);
        a1[i] = *(const uint4*)(pa[i] + 32);
        b1[i] = *(const uint4*)(pb[i] + 32);
    }

    int koff = 64;
    for (int s = 0; s < KSTEPS - 2; s += 2) {
        MFMA16(a0, b0)
#pragma unroll
        for (int i = 0; i < 4; ++i) {
            a0[i] = *(const uint4*)(pa[i] + koff);
            b0[i] = *(const uint4*)(pb[i] + koff);
        }
        MFMA16(a1, b1)
#pragma unroll
        for (int i = 0; i < 4; ++i) {
            a1[i] = *(const uint4*)(pa[i] + koff + 32);
            b1[i] = *(const uint4*)(pb[i] + koff + 32);
        }
        koff += 64;
    }
    MFMA16(a0, b0)
    MFMA16(a1, b1)

    float gm[16], bt[16];
#pragma unroll
    for (int i = 0; i < 4; ++i)
#pragma unroll
        for (int rg = 0; rg < 4; ++rg) {
            int row = mt * 64 + i * 16 + quad * 4 + rg;
            gm[i * 4 + rg] = gamma[row] * INV_;
            bt[i * 4 + rg] = beta[row];
        }

    if (MODE == 1) {
#pragma unroll
        for (int j = 0; j < 4; ++j) {
            int n = nt * 64 + j * 16 + ln;
            int bb = n >> 8;
            int cc = n & (C_ - 1);
            const ushort* gr = residT + (size_t)n * P_;       // gT row (b,c), indexed by o
            ushort* op = (ushort*)out + (size_t)bb * P_ * C_ + cc;
#pragma unroll
            for (int i = 0; i < 4; ++i) {
                int rbase = mt * 64 + i * 16 + quad * 4;
                ushort4 rv = *(const ushort4*)&gr[rbase];
                float rf[4] = {bf2f(rv.x), bf2f(rv.y), bf2f(rv.z), bf2f(rv.w)};
#pragma unroll
                for (int rg = 0; rg < 4; ++rg) {
                    int row = rbase + rg;
                    float v = fmaxf(acc[i][j][rg] * gm[i * 4 + rg] + bt[i * 4 + rg], 0.f) + rf[rg];
                    op[(size_t)row * C_] = f2bf(v);
                }
            }
        }
    } else {
#pragma unroll
        for (int j = 0; j < 4; ++j) {
            int n = nt * 64 + j * 16 + ln;
            int bb = n >> 11;
            int pp = n & (P_ - 1);
            float* op = (float*)out + (size_t)bb * C_ * P_ + pp;
#pragma unroll
            for (int i = 0; i < 4; ++i)
#pragma unroll
                for (int rg = 0; rg < 4; ++rg) {
                    int row = mt * 64 + i * 16 + quad * 4 + rg;
                    op[(size_t)row * P_] =
                        fmaxf(acc[i][j][rg] * gm[i * 4 + rg] + bt[i * 4 + rg], 0.f);
                }
        }
    }
}

// out[b][d][hw] = pos ? r[b][d][pos-1] : x[b][d][hw]
__global__ __launch_bounds__(256) void output_kernel(const float* __restrict__ x,
                                                     const int* __restrict__ pos,
                                                     const float* __restrict__ r,
                                                     float* __restrict__ out) {
    size_t v = (size_t)blockIdx.x * 256 + threadIdx.x;
    size_t e0 = v * 4;
    int hw = (int)(e0 & (HW_ - 1));
    int bc = (int)(e0 >> 14);
    int d = bc & (C_ - 1);
    int b = bc >> 8;
    float4 xv = *(const float4*)&x[e0];
    int4 pv = *(const int4*)&pos[b * HW_ + hw];
    const float* rrow = r + ((size_t)b * C_ + d) * P_;
    float4 ov = xv;
    if (pv.x) ov.x = rrow[pv.x - 1];
    if (pv.y) ov.y = rrow[pv.y - 1];
    if (pv.z) ov.z = rrow[pv.z - 1];
    if (pv.w) ov.w = rrow[pv.w - 1];
    *(float4*)&out[e0] = ov;
}

extern "C" void kernel_launch(void* const* d_in, const int* in_sizes, int n_in,
                              void* d_out, int out_size, void* d_ws, size_t ws_size,
                              hipStream_t stream) {
    const float* x    = (const float*)d_in[0];
    const float* edge = (const float*)d_in[1];
    const float* Wadj = (const float*)d_in[2];
    const float* ga   = (const float*)d_in[3];
    const float* be   = (const float*)d_in[4];
    const float* Wg   = (const float*)d_in[5];
    const float* gw   = (const float*)d_in[6];
    const float* bw   = (const float*)d_in[7];
    float* out = (float*)d_out;

    char* ws = (char*)d_ws;
    int*                ncand = (int*)(ws + OFF_NCAND);
    unsigned long long* cand  = (unsigned long long*)(ws + OFF_CAND);
    int*                topk  = (int*)(ws + OFF_TOPK);
    int*                pos   = (int*)(ws + OFF_POS);
    int*                rankb = (int*)(ws + OFF_RANK);
    ushort*             gT    = (ushort*)(ws + OFF_GT);
    ushort*             z2    = (ushort*)(ws + OFF_Z2);
    ushort*             WadjB = (ushort*)(ws + OFF_WADJB);
    ushort*             WgB   = (ushort*)(ws + OFF_WGB);
    float*              rbuf  = (float*)(ws + OFF_R);

    convert_bf16_kernel<<<P_ * P_ / 4 / 256, 256, 0, stream>>>(Wadj, WadjB);
    convert_bf16_kernel<<<C_ * C_ / 4 / 256, 256, 0, stream>>>(Wg, WgB);
    zero_ws_kernel<<<(B_ * HW_ + 255) / 256, 256, 0, stream>>>(pos, rankb, ncand);
    compact_kernel<<<B_ * 64, 256, 0, stream>>>(edge, cand, ncand);
    {
        dim3 grid(64, 64, B_);
        rank_partial_kernel<<<grid, 256, 0, stream>>>(cand, ncand, rankb);
    }
    {
        dim3 grid(64, B_);
        rank_finalize_kernel<<<grid, 256, 0, stream>>>(cand, ncand, rankb, topk, pos);
    }
    fallback_kernel<<<B_, 64, 0, stream>>>(edge, ncand, topk, pos);
    gather_lds_kernel<<<B_ * C_, 256, 0, stream>>>(x, topk, gT);

    // GEMM1: M=2048, N=1024 (b,c), K=2048 -> 32x16 wave tiles = 512 waves
    gemm_wave_kernel<1, 2048, 16><<<512, 64, 0, stream>>>(WadjB, gT, ga, be, gT, z2);
    // GEMM2: M=256, N=8192 (b,p), K=256 -> 4x128 wave tiles = 512 waves
    gemm_wave_kernel<2, 256, 128><<<512, 64, 0, stream>>>(WgB, z2, gw, bw, nullptr, rbuf);

    output_kernel<<<(B_ * C_ * HW_) / 4 / 256, 256, 0, stream>>>(x, pos, rbuf, out);
}